// Round 8
// baseline (52547.205 us; speedup 1.0000x reference)
//
#include <hip/hip_runtime.h>
#include <math.h>

// ESN reservoir recurrence, persistent-kernel, one-line mailbox protocol.
// x_{s+1} = 0.3*x_s + 0.7*tanh(0.9*W @ x_s + win0 * u[s])
// out[d][s-1001] = x_{s+1}[d] for s >= 1001   (out is 900 x 29999, row-major)
//
// Protocol (rounds 0-7 verified): 60 blocks x 15 rows; per step each block
// publishes ONE 64B line (15 x + float tag) at system scope (sc0 sc1) —
// anything weaker never observes the stores (rounds 1/2).
//
// THIS ROUND: registers-direct consumption. The matvec chunks
// (padded float 4*lane+256k, k=0..3) ARE 16B mailbox chunks, so each wave
// polls the whole x straight into its matvec registers (4 loads/lane,
// offsets 0/1024/2048/3072B) and self-validates. Line L's data AND tag
// arrive in the SAME wave instruction (line L <=> k=L>>4), line-atomic.
// Deletes LDS staging + S1 barrier + ds_reads; waves run independently
// from detect to epilogue. res[] becomes parity-double-buffered (with S1
// gone, publish-read(s) vs epilogue-write(s+1) are both only S2-ordered;
// parity + S2(s+1) restores safety). Epilogue x_old = res[s&1][r]
// (same-thread write at s-1; bit-identical to the mailbox value).
// Depth-2 SET polling + relocated drain (rounds 5/7 proven) retained:
// straggler = 4 loads; wave 0 drains vmcnt(1) over its publish store.
// Tag exclusion: lines 60..63 never written (stay 0) -> skip their checks
// (k==3 && lane>>2 >= 12).

#define DIM        900
#define T_TOTAL    31000
#define DISCARD_P1 1001
#define OUT_T      29999
#define NBLK       60
#define ROWS_PB    15
#define NTHREADS   256
#define SR         0.9f
#define LEAKY      0.7f
#define RING_W     64

// Workspace (floats): [0..1023] parity-0 lines, [1024..2047] parity-1 lines.
// Line b = 16 floats: x[15 rows] + tag. Zero-init == state 0 with tag 0.0f.
#define XBUF_F    1024
#define WS_INIT_N 2048

typedef float vfloat4 __attribute__((ext_vector_type(4)));

__global__ void esn_init_ws(float* ws) {
    int i = threadIdx.x + blockIdx.x * blockDim.x;
    if (i < WS_INIT_N) ws[i] = 0.0f;
}

__device__ __forceinline__ void store_line16(float* p, vfloat4 v) {
    asm volatile("global_store_dwordx4 %0, %1, off sc0 sc1"
                 :: "v"(p), "v"(v) : "memory");
}

// Issue one full-x set: 4 chunks/lane at +0/+1024/+2048/+3072 bytes.
#define POLL_SET(c0, c1, c2, c3, srcp)                                  \
    asm volatile("global_load_dwordx4 %0, %4, off sc0 sc1\n\t"          \
                 "global_load_dwordx4 %1, %4, off offset:1024 sc0 sc1\n\t" \
                 "global_load_dwordx4 %2, %4, off offset:2048 sc0 sc1\n\t" \
                 "global_load_dwordx4 %3, %4, off offset:3072 sc0 sc1"  \
                 : "=v"(c0), "=v"(c1), "=v"(c2), "=v"(c3)               \
                 : "v"(srcp) : "memory")

// Wait until this set's 4 loads landed (other set's 4 still in flight).
#define WAIT_SET(c0, c1, c2, c3)                                        \
    asm volatile("s_waitcnt vmcnt(4)"                                   \
                 : "+v"(c0), "+v"(c1), "+v"(c2), "+v"(c3) :: "memory")

// All-lines tag check: tag lanes are lane&3==3; chunk k holds the tag of
// line (lane>>2)+16k; k<3 always valid, k==3 valid iff lane>>2 < 12.
#define TAG_OK(c0, c1, c2, c3, okvar)                                   \
    { bool ok_ = true;                                                  \
      if (lt)  ok_ = (c0.w == tag) & (c1.w == tag) & (c2.w == tag);     \
      if (t3v) ok_ = ok_ & (c3.w == tag);                               \
      okvar = __all(ok_); }

__launch_bounds__(NTHREADS, 1)
__global__ void esn_persistent(const float* __restrict__ W,
                               const float* __restrict__ W_in,
                               const float* __restrict__ u,
                               float* __restrict__ out,
                               float* xbuf)
{
    __shared__ float ring[ROWS_PB][RING_W + 1];   // output staging
    __shared__ __align__(16) float res[2][16];    // next line, dbuf by parity

    const int tid   = threadIdx.x;
    const int blk   = blockIdx.x;
    const int row0  = blk * ROWS_PB;
    const int wave  = tid >> 6;
    const int lane  = tid & 63;
    const int rbase = wave * 4;                   // rows rbase..rbase+3 (15=tag)

    // W in registers over the PADDED 960-col layout: padded index p ->
    // source p>>4, offset p&15; offset 15 is the tag column -> W := 0.
    vfloat4 wreg[4][4];
    #pragma unroll
    for (int r = 0; r < 4; ++r) {
        const int row = rbase + r;
        #pragma unroll
        for (int k = 0; k < 4; ++k) {
            const int p = 4 * lane + 256 * k;
            vfloat4 v = (vfloat4)0.0f;
            if (row < ROWS_PB) {
                #pragma unroll
                for (int j = 0; j < 4; ++j) {
                    const int pp  = p + j;
                    const int off = pp & 15;
                    if (pp < 960 && off < 15) {
                        const int col = (pp >> 4) * 15 + off;
                        v[j] = SR * W[(size_t)(row0 + row) * DIM + col];
                    }
                }
            }
            wreg[r][k] = v;
        }
    }
    float win0r = 0.0f;
    if (lane < 4 && rbase + lane < ROWS_PB)
        win0r = W_in[(size_t)(row0 + rbase + lane) * DIM];   // column 0

    // Tag-lane constants.
    const bool lt  = (lane & 3) == 3;
    const bool t3v = lt && ((lane >> 2) < 12);

    // res init: x_old(s=0)=0 read from res[0] by the SAME thread that
    // writes it here (lane<4 of each wave covers indices 0..15).
    if (lane < 4) { res[0][rbase + lane] = 0.0f; res[1][rbase + lane] = 0.0f; }
    __syncthreads();

    vfloat4 A0, A1, A2, A3, B0, B1, B2, B3;   // poll sets, live across tail

    for (int s = 0; s < T_TOTAL; ++s) {
        const float ut  = u[s];
        const float tag = (float)s;
        const float* src = xbuf + (size_t)(s & 1) * XBUF_F + 4 * lane;

        // ---- depth-2 set-pipelined poll straight into matvec registers ----
        vfloat4 xv0, xv1, xv2, xv3;
        POLL_SET(A0, A1, A2, A3, src);
        for (;;) {
            POLL_SET(B0, B1, B2, B3, src);
            WAIT_SET(A0, A1, A2, A3);
            bool ok;
            TAG_OK(A0, A1, A2, A3, ok);
            if (ok) { xv0 = A0; xv1 = A1; xv2 = A2; xv3 = A3; break; }
            POLL_SET(A0, A1, A2, A3, src);
            WAIT_SET(B0, B1, B2, B3);
            TAG_OK(B0, B1, B2, B3, ok);
            if (ok) { xv0 = B0; xv1 = B1; xv2 = B2; xv3 = B3; break; }
        }
        // straggler set (4 loads) stays in flight through the tail

        // ---- matvec: 4 rows/wave, all operands already in registers ----
        // (xv chunks = same bits as the old x_lds reads -> bitwise identical)
        float a0, a1, a2, a3;
        a0  = wreg[0][0].x * xv0.x + wreg[0][0].y * xv0.y
            + wreg[0][0].z * xv0.z + wreg[0][0].w * xv0.w;
        a1  = wreg[1][0].x * xv0.x + wreg[1][0].y * xv0.y
            + wreg[1][0].z * xv0.z + wreg[1][0].w * xv0.w;
        a2  = wreg[2][0].x * xv0.x + wreg[2][0].y * xv0.y
            + wreg[2][0].z * xv0.z + wreg[2][0].w * xv0.w;
        a3  = wreg[3][0].x * xv0.x + wreg[3][0].y * xv0.y
            + wreg[3][0].z * xv0.z + wreg[3][0].w * xv0.w;
        a0 += wreg[0][1].x * xv1.x + wreg[0][1].y * xv1.y
            + wreg[0][1].z * xv1.z + wreg[0][1].w * xv1.w;
        a1 += wreg[1][1].x * xv1.x + wreg[1][1].y * xv1.y
            + wreg[1][1].z * xv1.z + wreg[1][1].w * xv1.w;
        a2 += wreg[2][1].x * xv1.x + wreg[2][1].y * xv1.y
            + wreg[2][1].z * xv1.z + wreg[2][1].w * xv1.w;
        a3 += wreg[3][1].x * xv1.x + wreg[3][1].y * xv1.y
            + wreg[3][1].z * xv1.z + wreg[3][1].w * xv1.w;
        a0 += wreg[0][2].x * xv2.x + wreg[0][2].y * xv2.y
            + wreg[0][2].z * xv2.z + wreg[0][2].w * xv2.w;
        a1 += wreg[1][2].x * xv2.x + wreg[1][2].y * xv2.y
            + wreg[1][2].z * xv2.z + wreg[1][2].w * xv2.w;
        a2 += wreg[2][2].x * xv2.x + wreg[2][2].y * xv2.y
            + wreg[2][2].z * xv2.z + wreg[2][2].w * xv2.w;
        a3 += wreg[3][2].x * xv2.x + wreg[3][2].y * xv2.y
            + wreg[3][2].z * xv2.z + wreg[3][2].w * xv2.w;
        a0 += wreg[0][3].x * xv3.x + wreg[0][3].y * xv3.y
            + wreg[0][3].z * xv3.z + wreg[0][3].w * xv3.w;
        a1 += wreg[1][3].x * xv3.x + wreg[1][3].y * xv3.y
            + wreg[1][3].z * xv3.z + wreg[1][3].w * xv3.w;
        a2 += wreg[2][3].x * xv3.x + wreg[2][3].y * xv3.y
            + wreg[2][3].z * xv3.z + wreg[2][3].w * xv3.w;
        a3 += wreg[3][3].x * xv3.x + wreg[3][3].y * xv3.y
            + wreg[3][3].z * xv3.z + wreg[3][3].w * xv3.w;

        // ---- merged butterfly (bitwise identical to 4 full trees) ----
        a0 += __shfl_xor(a0, 1, 64);
        a1 += __shfl_xor(a1, 1, 64);
        a2 += __shfl_xor(a2, 1, 64);
        a3 += __shfl_xor(a3, 1, 64);
        float m01 = (lane & 1) ? a1 : a0;
        float m23 = (lane & 1) ? a3 : a2;
        m01 += __shfl_xor(m01, 2, 64);
        m23 += __shfl_xor(m23, 2, 64);
        float m = (lane & 2) ? m23 : m01;
        #pragma unroll
        for (int off = 4; off < 64; off <<= 1)
            m += __shfl_xor(m, off, 64);
        // lane j (0..3): m = full dot product for row rbase+j

        // ---- epilogue: lanes 0..3 per wave finish one row each ----
        if (lane < 4) {
            const int r = rbase + lane;                 // 0..15
            float* resp = res[(s + 1) & 1];
            if (r < ROWS_PB) {
                float z = m + win0r * ut;
                z = fminf(fmaxf(z, -9.0f), 9.0f);
                const float e  = __expf(2.0f * z);
                const float th = (e - 1.0f) / (e + 1.0f);
                const float xo = res[s & 1][r];         // own x_s (same bits)
                const float xn = (1.0f - LEAKY) * xo + LEAKY * th;
                resp[r] = xn;
                if (s >= DISCARD_P1)
                    ring[r][(s - DISCARD_P1) & (RING_W - 1)] = xn;
            } else {
                resp[15] = (float)(s + 1);              // tag for new state
            }
        }
        __syncthreads();   // S2: res complete (the step's only barrier)

        // ---- publish: ONE 64B store carries 15 values + tag ----
        if (tid < 4) {
            const vfloat4 rv =
                *reinterpret_cast<const vfloat4*>(&res[(s + 1) & 1][4 * tid]);
            store_line16(xbuf + (size_t)((s + 1) & 1) * XBUF_F
                              + (size_t)blk * 16 + 4 * tid, rv);
        }

        // ---- output flush: after publish -> off the inter-block path ----
        if (s >= DISCARD_P1) {
            const int  c    = s - DISCARD_P1;
            const bool last = (s == T_TOTAL - 1);
            if ((c & (RING_W - 1)) == (RING_W - 1) || last) {
                const int len = (c & (RING_W - 1)) + 1;
                const int c0  = c - len + 1;
                if (len == RING_W) {
                    for (int i = tid; i < ROWS_PB * RING_W; i += NTHREADS) {
                        const int row = i >> 6, col = i & (RING_W - 1);
                        out[(size_t)(row0 + row) * OUT_T + c0 + col] =
                            ring[row][col];
                    }
                } else {
                    for (int i = tid; i < ROWS_PB * len; i += NTHREADS) {
                        const int row = i / len, col = i % len;
                        out[(size_t)(row0 + row) * OUT_T + c0 + col] =
                            ring[row][col];
                    }
                }
            }
        }

        // ---- relocated drain (round-7 proven): only hazard is next step's
        // slot reuse. Straggler set (4 loads) is OLDER than the publish
        // store / flush stores, so wave 0's vmcnt(1) (newest = a store) and
        // waves 1-3's vmcnt(0) both guarantee the stragglers are done.
        if (wave == 0)
            asm volatile("s_waitcnt vmcnt(1)"
                         : "+v"(A0), "+v"(A1), "+v"(A2), "+v"(A3),
                           "+v"(B0), "+v"(B1), "+v"(B2), "+v"(B3) :: "memory");
        else
            asm volatile("s_waitcnt vmcnt(0)"
                         : "+v"(A0), "+v"(A1), "+v"(A2), "+v"(A3),
                           "+v"(B0), "+v"(B1), "+v"(B2), "+v"(B3) :: "memory");
        // ring flush-read(s) vs ring write(s+64): ordered by intervening S2s.
    }
}

extern "C" void kernel_launch(void* const* d_in, const int* in_sizes, int n_in,
                              void* d_out, int out_size, void* d_ws, size_t ws_size,
                              hipStream_t stream) {
    const float* W    = (const float*)d_in[0];
    const float* W_in = (const float*)d_in[1];
    const float* u    = (const float*)d_in[2];
    float* out = (float*)d_out;
    float* ws  = (float*)d_ws;

    esn_init_ws<<<WS_INIT_N / 256, 256, 0, stream>>>(ws);
    esn_persistent<<<NBLK, NTHREADS, 0, stream>>>(W, W_in, u, out, ws);
}